// Round 8
// baseline (837.771 us; speedup 1.0000x reference)
//
#include <hip/hip_runtime.h>
#include <math.h>

#define BB 512
#define SS 200
#define DDIM 64
#define HD 32
#define LL 2
#define NROWS (BB * SS)   // 102400
#define EPS 1e-8f
#define CC 0.001f
#define GRAM_NB 256

// ---------------- static device buffers (activations) ----------------
__device__ float g_x[NROWS * DDIM];
__device__ float g_qin[NROWS * DDIM];
__device__ float g_q[NROWS * DDIM];
__device__ float g_k[NROWS * DDIM];
__device__ float g_v[NROWS * DDIM];
__device__ float g_ctx[NROWS * DDIM];
__device__ float g_gpart[GRAM_NB * 4096];   // gram per-block partials

// ---------------- helpers ----------------
__device__ __forceinline__ float wave_sum(float v) {
#pragma unroll
    for (int o = 32; o > 0; o >>= 1) v += __shfl_xor(v, o, 64);
    return v;
}
__device__ __forceinline__ float wave_max(float v) {
#pragma unroll
    for (int o = 32; o > 0; o >>= 1) v = fmaxf(v, __shfl_xor(v, o, 64));
    return v;
}

// bf16 pack/unpack (RNE)
__device__ __forceinline__ unsigned short f2b(float f) {
    unsigned u = __float_as_uint(f);
    return (unsigned short)((u + 0x7FFFu + ((u >> 16) & 1u)) >> 16);
}
__device__ __forceinline__ unsigned pk2(float a, float b) {
    return (unsigned)f2b(a) | ((unsigned)f2b(b) << 16);
}
__device__ __forceinline__ float blo(unsigned u) { return __uint_as_float(u << 16); }
__device__ __forceinline__ float bhi(unsigned u) { return __uint_as_float(u & 0xFFFF0000u); }

// ---------------- embedding (float4) ----------------
__global__ __launch_bounds__(256) void embed_kernel(const int* __restrict__ log_seqs,
                                                    const float* __restrict__ item_emb,
                                                    const float* __restrict__ pos_emb,
                                                    float* __restrict__ x) {
    int tid = blockIdx.x * 256 + threadIdx.x;   // over NROWS*16
    int row = tid >> 4, q4 = tid & 15;
    int s = row % SS;
    int li = log_seqs[row];
    int poss = li ? (s + 1) : 0;
    float4 e = *(const float4*)&item_emb[li * DDIM + q4 * 4];
    float4 p = *(const float4*)&pos_emb[poss * DDIM + q4 * 4];
    float4 o;
    o.x = e.x * 8.0f + p.x; o.y = e.y * 8.0f + p.y;
    o.z = e.z * 8.0f + p.z; o.w = e.w * 8.0f + p.w;
    *(float4*)&x[row * DDIM + q4 * 4] = o;
}

// ---------------- tile staging helpers ----------------
__device__ __forceinline__ void stage_in(const float* __restrict__ G, float (* __restrict__ tile)[68],
                                         int t, long row0) {
#pragma unroll
    for (int rep = 0; rep < 4; ++rep) {
        int idx = t + rep * 256;
        int c = idx >> 4, d4 = (idx & 15) * 4;
        *(float4*)&tile[c][d4] = *(const float4*)&G[(row0 + c) * DDIM + d4];
    }
}

// Stage W (64 out x 64 in, row-major) TRANSPOSED into wt[d][c], via 4x4 block transpose.
__device__ __forceinline__ void stage_wT(const float* __restrict__ Wg, float (* __restrict__ wt)[68], int t) {
    int bi = t & 15, bj = t >> 4;   // bi: c-block, bj: d-block
    float rv[4][4];
#pragma unroll
    for (int e = 0; e < 4; ++e)
        *(float4*)rv[e] = *(const float4*)&Wg[(bi * 4 + e) * DDIM + bj * 4];
#pragma unroll
    for (int e = 0; e < 4; ++e) {
        float4 o;
        o.x = rv[0][e]; o.y = rv[1][e]; o.z = rv[2][e]; o.w = rv[3][e];
        *(float4*)&wt[bj * 4 + e][bi * 4] = o;
    }
}

// acc[i][j] += sum_d A[r0+i][d] * W[d][c0+j]   (W stored transposed: wt[d][c])
__device__ __forceinline__ void gemm_tile(const float (* __restrict__ A)[68],
                                          const float (* __restrict__ W)[68],
                                          int r0, int c0, float acc[4][4]) {
#pragma unroll
    for (int d = 0; d < 64; d += 4) {
        float4 a[4], wv[4];
#pragma unroll
        for (int i = 0; i < 4; ++i) a[i] = *(const float4*)&A[r0 + i][d];
#pragma unroll
        for (int tt = 0; tt < 4; ++tt) wv[tt] = *(const float4*)&W[d + tt][c0];
#pragma unroll
        for (int i = 0; i < 4; ++i) {
            float av[4] = {a[i].x, a[i].y, a[i].z, a[i].w};
#pragma unroll
            for (int tt = 0; tt < 4; ++tt) {
                acc[i][0] += av[tt] * wv[tt].x;
                acc[i][1] += av[tt] * wv[tt].y;
                acc[i][2] += av[tt] * wv[tt].z;
                acc[i][3] += av[tt] * wv[tt].w;
            }
        }
    }
}

// LayerNorm rows of src -> dst (thread t owns row t>>2, 16-col chunk (t&3)*16).
__device__ __forceinline__ void ln_rows(const float (* __restrict__ src)[68], float (* __restrict__ dst)[68],
                                        const float* __restrict__ w_s, const float* __restrict__ b_s,
                                        int t, float* __restrict__ save) {
    int rr = t >> 2, qd = (t & 3) * 16;
    float4 v[4];
#pragma unroll
    for (int g = 0; g < 4; ++g) v[g] = *(const float4*)&src[rr][qd + g * 4];
    float s1 = 0.f, s2 = 0.f;
#pragma unroll
    for (int g = 0; g < 4; ++g) {
        s1 += (v[g].x + v[g].y) + (v[g].z + v[g].w);
        s2 += (v[g].x * v[g].x + v[g].y * v[g].y) + (v[g].z * v[g].z + v[g].w * v[g].w);
    }
    s1 += __shfl_xor(s1, 1, 64); s1 += __shfl_xor(s1, 2, 64);
    s2 += __shfl_xor(s2, 1, 64); s2 += __shfl_xor(s2, 2, 64);
    float m = s1 * (1.f / 64.f);
    float var = s2 * (1.f / 64.f) - m * m;
    float rs = rsqrtf(var + EPS);
#pragma unroll
    for (int g = 0; g < 4; ++g) {
        float4 w4 = *(const float4*)&w_s[qd + g * 4];
        float4 b4 = *(const float4*)&b_s[qd + g * 4];
        float4 o;
        o.x = (v[g].x - m) * rs * w4.x + b4.x;
        o.y = (v[g].y - m) * rs * w4.y + b4.y;
        o.z = (v[g].z - m) * rs * w4.z + b4.z;
        o.w = (v[g].w - m) * rs * w4.w + b4.w;
        *(float4*)&dst[rr][qd + g * 4] = o;
        if (save) *(float4*)&save[rr * DDIM + qd + g * 4] = o;
    }
}

// Dual LayerNorm: a := LN1(a), b := LN2(a_old)
__device__ __forceinline__ void ln_rows2(float (* __restrict__ a)[68], float (* __restrict__ b)[68],
                                         const float* __restrict__ w1, const float* __restrict__ b1,
                                         const float* __restrict__ w2, const float* __restrict__ b2, int t) {
    int rr = t >> 2, qd = (t & 3) * 16;
    float4 v[4];
#pragma unroll
    for (int g = 0; g < 4; ++g) v[g] = *(const float4*)&a[rr][qd + g * 4];
    float s1 = 0.f, s2 = 0.f;
#pragma unroll
    for (int g = 0; g < 4; ++g) {
        s1 += (v[g].x + v[g].y) + (v[g].z + v[g].w);
        s2 += (v[g].x * v[g].x + v[g].y * v[g].y) + (v[g].z * v[g].z + v[g].w * v[g].w);
    }
    s1 += __shfl_xor(s1, 1, 64); s1 += __shfl_xor(s1, 2, 64);
    s2 += __shfl_xor(s2, 1, 64); s2 += __shfl_xor(s2, 2, 64);
    float m = s1 * (1.f / 64.f);
    float var = s2 * (1.f / 64.f) - m * m;
    float rs = rsqrtf(var + EPS);
#pragma unroll
    for (int g = 0; g < 4; ++g) {
        float4 w14 = *(const float4*)&w1[qd + g * 4];
        float4 b14 = *(const float4*)&b1[qd + g * 4];
        float4 w24 = *(const float4*)&w2[qd + g * 4];
        float4 b24 = *(const float4*)&b2[qd + g * 4];
        float nx = (v[g].x - m) * rs, ny = (v[g].y - m) * rs, nz = (v[g].z - m) * rs, nw = (v[g].w - m) * rs;
        float4 o1, o2;
        o1.x = nx * w14.x + b14.x; o1.y = ny * w14.y + b14.y; o1.z = nz * w14.z + b14.z; o1.w = nw * w14.w + b14.w;
        o2.x = nx * w24.x + b24.x; o2.y = ny * w24.y + b24.y; o2.z = nz * w24.z + b24.z; o2.w = nw * w24.w + b24.w;
        *(float4*)&a[rr][qd + g * 4] = o1;
        *(float4*)&b[rr][qd + g * 4] = o2;
    }
}

// ---------------- fused QKV ----------------
__global__ __launch_bounds__(256) void qkv_fused(const float* __restrict__ x,
                                                 const float* __restrict__ Wqkv,
                                                 const float* __restrict__ Bqkv,
                                                 const float* __restrict__ lnw,
                                                 const float* __restrict__ lnb,
                                                 float* __restrict__ qin,
                                                 float* __restrict__ qo,
                                                 float* __restrict__ ko,
                                                 float* __restrict__ vo) {
    __shared__ float A[64][68], B[64][68], W[64][68];
    __shared__ float lw[64], lb[64];
    int t = threadIdx.x;
    long row0 = (long)blockIdx.x * 64;
    stage_in(x, A, t, row0);
    stage_wT(Wqkv, W, t);
    if (t < 64) { lw[t] = lnw[t]; lb[t] = lnb[t]; }
    __syncthreads();
    ln_rows(A, B, lw, lb, t, qin + row0 * DDIM);
    __syncthreads();
    int tx = t & 15, ty = t >> 4, r0 = ty * 4, c0 = tx * 4;
    {
        float acc[4][4] = {};
        gemm_tile(B, W, r0, c0, acc);
        float4 b4 = *(const float4*)&Bqkv[c0];
        float bv[4] = {b4.x, b4.y, b4.z, b4.w};
#pragma unroll
        for (int i = 0; i < 4; ++i) {
            float4 o; o.x = acc[i][0] + bv[0]; o.y = acc[i][1] + bv[1]; o.z = acc[i][2] + bv[2]; o.w = acc[i][3] + bv[3];
            *(float4*)&qo[(row0 + r0 + i) * DDIM + c0] = o;
        }
    }
    __syncthreads();
    stage_wT(Wqkv + 4096, W, t);
    __syncthreads();
    {
        float acc[4][4] = {};
        gemm_tile(A, W, r0, c0, acc);
        float4 b4 = *(const float4*)&Bqkv[64 + c0];
        float bv[4] = {b4.x, b4.y, b4.z, b4.w};
#pragma unroll
        for (int i = 0; i < 4; ++i) {
            float4 o; o.x = acc[i][0] + bv[0]; o.y = acc[i][1] + bv[1]; o.z = acc[i][2] + bv[2]; o.w = acc[i][3] + bv[3];
            *(float4*)&ko[(row0 + r0 + i) * DDIM + c0] = o;
        }
    }
    __syncthreads();
    stage_wT(Wqkv + 8192, W, t);
    __syncthreads();
    {
        float acc[4][4] = {};
        gemm_tile(A, W, r0, c0, acc);
        float4 b4 = *(const float4*)&Bqkv[128 + c0];
        float bv[4] = {b4.x, b4.y, b4.z, b4.w};
#pragma unroll
        for (int i = 0; i < 4; ++i) {
            float4 o; o.x = acc[i][0] + bv[0]; o.y = acc[i][1] + bv[1]; o.z = acc[i][2] + bv[2]; o.w = acc[i][3] + bv[3];
            *(float4*)&vo[(row0 + r0 + i) * DDIM + c0] = o;
        }
    }
}

// ---------------- fused out-proj + FFN ----------------
__global__ __launch_bounds__(256) void ffn_fused(const float* __restrict__ ctx,
                                                 const float* __restrict__ qin,
                                                 const float* __restrict__ Wo, const float* __restrict__ bo,
                                                 const float* __restrict__ W1, const float* __restrict__ b1,
                                                 const float* __restrict__ W2, const float* __restrict__ b2,
                                                 const float* __restrict__ l1w, const float* __restrict__ l1b,
                                                 const float* __restrict__ l2w, const float* __restrict__ l2b,
                                                 float* __restrict__ xout) {
    __shared__ float A[64][68], B[64][68], W[64][68];
    __shared__ float w1s[64], b1s[64], w2s[64], b2s[64];
    int t = threadIdx.x;
    long row0 = (long)blockIdx.x * 64;
    stage_in(ctx, A, t, row0);
    stage_in(qin, B, t, row0);
    stage_wT(Wo, W, t);
    if (t < 64) { w1s[t] = l1w[t]; b1s[t] = l1b[t]; w2s[t] = l2w[t]; b2s[t] = l2b[t]; }
    __syncthreads();
    int tx = t & 15, ty = t >> 4, r0 = ty * 4, c0 = tx * 4;
    float x1[4][4] = {};
    gemm_tile(A, W, r0, c0, x1);
    {
        float4 b4 = *(const float4*)&bo[c0];
        float bv[4] = {b4.x, b4.y, b4.z, b4.w};
#pragma unroll
        for (int i = 0; i < 4; ++i)
#pragma unroll
            for (int j = 0; j < 4; ++j) x1[i][j] += bv[j] + B[r0 + i][c0 + j];
    }
    __syncthreads();
#pragma unroll
    for (int i = 0; i < 4; ++i) {
        float4 o; o.x = x1[i][0]; o.y = x1[i][1]; o.z = x1[i][2]; o.w = x1[i][3];
        *(float4*)&A[r0 + i][c0] = o;
    }
    __syncthreads();
    ln_rows2(A, B, w1s, b1s, w2s, b2s, t);
    stage_wT(W1, W, t);
    __syncthreads();
    float h[4][4] = {};
    gemm_tile(A, W, r0, c0, h);
    {
        float4 b4 = *(const float4*)&b1[c0];
        float bv[4] = {b4.x, b4.y, b4.z, b4.w};
#pragma unroll
        for (int i = 0; i < 4; ++i)
#pragma unroll
            for (int j = 0; j < 4; ++j) h[i][j] = fmaxf(h[i][j] + bv[j], 0.f);
    }
    __syncthreads();
#pragma unroll
    for (int i = 0; i < 4; ++i) {
        float4 o; o.x = h[i][0]; o.y = h[i][1]; o.z = h[i][2]; o.w = h[i][3];
        *(float4*)&A[r0 + i][c0] = o;
    }
    stage_wT(W2, W, t);
    __syncthreads();
    float o3[4][4] = {};
    gemm_tile(A, W, r0, c0, o3);
    {
        float4 b4 = *(const float4*)&b2[c0];
        float bv[4] = {b4.x, b4.y, b4.z, b4.w};
#pragma unroll
        for (int i = 0; i < 4; ++i) {
            float4 o;
            o.x = o3[i][0] + bv[0] + B[r0 + i][c0 + 0];
            o.y = o3[i][1] + bv[1] + B[r0 + i][c0 + 1];
            o.z = o3[i][2] + bv[2] + B[r0 + i][c0 + 2];
            o.w = o3[i][3] + bv[3] + B[r0 + i][c0 + 3];
            *(float4*)&xout[(row0 + r0 + i) * DDIM + c0] = o;
        }
    }
}

// ---------------- causal attention, one block per (b, head), 8 waves ----------------
// K, V, A_s held in LDS as bf16 (43.2 KB total -> 3 blocks/CU). fp32 math throughout.
// QK chunk-major: K row unpacked to 32 fp32 regs once per chunk, reused for 4 Q-rows.
// PV: V b64 reads (4 bf16), A_s u16 reads; 4 rows share each V read.
__global__ __launch_bounds__(512, 6) void attn_kernel(const float* __restrict__ q,
                                                      const float* __restrict__ k,
                                                      const float* __restrict__ v,
                                                      float* __restrict__ ctx) {
    __shared__ unsigned Kb[SS * 20];        // bf16x2, row stride 20 uints (80B, 16B-aligned)
    __shared__ unsigned Vb[SS * 18];        // bf16x2, row stride 18 uints (72B, 8B-aligned)
    __shared__ unsigned short As[8][4][SS]; // softmax weights bf16
    int b = blockIdx.x >> 1, h = blockIdx.x & 1;
    int t = threadIdx.x;
    const long base = (long)b * (SS * DDIM) + h * HD;
    for (int i = t; i < SS * 8; i += 512) {
        int kk = i >> 3, dq = i & 7;
        float4 k4 = *(const float4*)&k[base + kk * DDIM + dq * 4];
        *(uint2*)&Kb[kk * 20 + dq * 2] = make_uint2(pk2(k4.x, k4.y), pk2(k4.z, k4.w));
        float4 v4 = *(const float4*)&v[base + kk * DDIM + dq * 4];
        *(uint2*)&Vb[kk * 18 + dq * 2] = make_uint2(pk2(v4.x, v4.y), pk2(v4.z, v4.w));
    }
    __syncthreads();
    int w = t >> 6, lane = t & 63;
    const float scale = 0.17677669529663687f;   // 1/sqrt(32)
    for (int G = w; G < SS / 4; G += 8) {
        int r3 = 4 * G + 3;
        int ncb3 = (r3 >> 6) + 1;            // 1..4
        float sc[4][4];
#pragma unroll
        for (int i = 0; i < 4; ++i)
#pragma unroll
            for (int c = 0; c < 4; ++c) sc[i][c] = -1e30f;
        // ---- QK, chunk-major ----
#pragma unroll
        for (int c = 0; c < 4; ++c) {
            if (c < ncb3) {
                int kk = lane + c * 64;
                if (kk <= r3) {
                    const unsigned* kr = &Kb[kk * 20];
                    uint4 ku[4];
                    ku[0] = *(const uint4*)(kr);
                    ku[1] = *(const uint4*)(kr + 4);
                    ku[2] = *(const uint4*)(kr + 8);
                    ku[3] = *(const uint4*)(kr + 12);
                    float kf[32];
#pragma unroll
                    for (int g = 0; g < 4; ++g) {
                        kf[g * 8 + 0] = blo(ku[g].x); kf[g * 8 + 1] = bhi(ku[g].x);
                        kf[g * 8 + 2] = blo(ku[g].y); kf[g * 8 + 3] = bhi(ku[g].y);
                        kf[g * 8 + 4] = blo(ku[g].z); kf[g * 8 + 5] = bhi(ku[g].z);
                        kf[g * 8 + 6] = blo(ku[g].w); kf[g * 8 + 7] = bhi(ku[g].w);
                    }
#pragma unroll
                    for (int i = 0; i < 4; ++i) {
                        int r = 4 * G + i;
                        if (kk <= r) {
                            const float4* qp = (const float4*)&q[base + r * DDIM];
                            float d0 = 0.f, d1 = 0.f, d2 = 0.f, d3 = 0.f;
#pragma unroll
                            for (int j = 0; j < 8; ++j) {
                                float4 qq = qp[j];
                                d0 += qq.x * kf[j * 4 + 0];
                                d1 += qq.y * kf[j * 4 + 1];
                                d2 += qq.z * kf[j * 4 + 2];
                                d3 += qq.w * kf[j * 4 + 3];
                            }
                            sc[i][c] = ((d0 + d1) + (d2 + d3)) * scale;
                        }
                    }
                }
            }
        }
        // ---- softmax per row, write bf16 weights ----
#pragma unroll
        for (int i = 0; i < 4; ++i) {
            int r = 4 * G + i;
            float m = -1e30f;
#pragma unroll
            for (int c = 0; c < 4; ++c) if (c < ncb3) m = fmaxf(m, sc[i][c]);
            m = wave_max(m);
            float sum = 0.f;
#pragma unroll
            for (int c = 0; c < 4; ++c) {
                if (c < ncb3) {
                    int kk = lane + c * 64;
                    if (kk <= r) { sc[i][c] = __expf(sc[i][c] - m); sum += sc[i][c]; }
                }
            }
            sum = wave_sum(sum);
            float inv = 1.f / sum;
#pragma unroll
            for (int c = 0; c < 4; ++c) {
                if (c < ncb3) {
                    int kk = lane + c * 64;
                    if (kk <= r3) As[w][i][kk] = (kk <= r) ? f2b(sc[i][c] * inv) : (unsigned short)0;
                }
            }
        }
        // ---- PV: 4 rows share each V read ----
        int d4 = lane & 7, ko = lane >> 3;
        float4 acc0 = {0,0,0,0}, acc1 = {0,0,0,0}, acc2 = {0,0,0,0}, acc3 = {0,0,0,0};
        for (int kk = ko; kk <= r3; kk += 8) {
            uint2 vv = *(const uint2*)&Vb[kk * 18 + d4 * 2];
            float v0 = blo(vv.x), v1 = bhi(vv.x), v2 = blo(vv.y), v3 = bhi(vv.y);
            float a0 = __uint_as_float(((unsigned)As[w][0][kk]) << 16);
            float a1 = __uint_as_float(((unsigned)As[w][1][kk]) << 16);
            float a2 = __uint_as_float(((unsigned)As[w][2][kk]) << 16);
            float a3 = __uint_as_float(((unsigned)As[w][3][kk]) << 16);
            acc0.x += a0 * v0; acc0.y += a0 * v1; acc0.z += a0 * v2; acc0.w += a0 * v3;
            acc1.x += a1 * v0; acc1.y += a1 * v1; acc1.z += a1 * v2; acc1.w += a1 * v3;
            acc2.x += a2 * v0; acc2.y += a2 * v1; acc2.z += a2 * v2; acc2.w += a2 * v3;
            acc3.x += a3 * v0; acc3.y += a3 * v1; acc3.z += a3 * v2; acc3.w += a3 * v3;
        }
        float4* accs[4] = {&acc0, &acc1, &acc2, &acc3};
#pragma unroll
        for (int i = 0; i < 4; ++i) {
            float4& a = *accs[i];
#pragma unroll
            for (int o = 8; o <= 32; o <<= 1) {
                a.x += __shfl_xor(a.x, o, 64);
                a.y += __shfl_xor(a.y, o, 64);
                a.z += __shfl_xor(a.z, o, 64);
                a.w += __shfl_xor(a.w, o, 64);
            }
        }
        if (ko == 0) {
#pragma unroll
            for (int i = 0; i < 4; ++i) {
                int r = 4 * G + i;
                *(float4*)&ctx[base + r * DDIM + d4 * 4] = *accs[i];
            }
        }
    }
}

// ---------------- Gram matrix partials ----------------
__global__ __launch_bounds__(256) void gram_kernel(const float* __restrict__ A, int nrows,
                                                   float* __restrict__ part) {
    __shared__ float rows[16][64];
    int t = threadIdx.x;
    int i = t >> 2;            // 0..63
    int jb = (t & 3) * 16;     // 0/16/32/48
    float acc[16] = {};
    for (long base = (long)blockIdx.x * 16; base < nrows; base += (long)GRAM_NB * 16) {
        {
            int rr = t >> 4, d4 = (t & 15) * 4;
            long gr = base + rr;
            float4 vv = make_float4(0.f, 0.f, 0.f, 0.f);
            if (gr < nrows) vv = *(const float4*)&A[gr * DDIM + d4];
            *(float4*)&rows[rr][d4] = vv;
        }
        __syncthreads();
#pragma unroll
        for (int rr = 0; rr < 16; ++rr) {
            float ai = rows[rr][i];
            float4 r0 = *(const float4*)&rows[rr][jb];
            float4 r1 = *(const float4*)&rows[rr][jb + 4];
            float4 r2 = *(const float4*)&rows[rr][jb + 8];
            float4 r3 = *(const float4*)&rows[rr][jb + 12];
            acc[0] += ai * r0.x; acc[1] += ai * r0.y; acc[2] += ai * r0.z; acc[3] += ai * r0.w;
            acc[4] += ai * r1.x; acc[5] += ai * r1.y; acc[6] += ai * r1.z; acc[7] += ai * r1.w;
            acc[8] += ai * r2.x; acc[9] += ai * r2.y; acc[10] += ai * r2.z; acc[11] += ai * r2.w;
            acc[12] += ai * r3.x; acc[13] += ai * r3.y; acc[14] += ai * r3.z; acc[15] += ai * r3.w;
        }
        __syncthreads();
    }
    float* slab = part + (long)blockIdx.x * 4096 + i * 64 + jb;
#pragma unroll
    for (int g = 0; g < 4; ++g) {
        float4 o; o.x = acc[g * 4]; o.y = acc[g * 4 + 1]; o.z = acc[g * 4 + 2]; o.w = acc[g * 4 + 3];
        *(float4*)&slab[g * 4] = o;
    }
}

// out[p] = sum_b part[b*4096+p]
__global__ __launch_bounds__(256) void gram_reduce(const float* __restrict__ part,
                                                   float* __restrict__ out) {
    int p = blockIdx.x * 256 + threadIdx.x;   // 16 blocks
    float s = 0.f;
    for (int b = 0; b < GRAM_NB; ++b) s += part[(long)b * 4096 + p];
    out[p] = s;
}

// ---------------- right(): per-block partial sums of (1-C)ps^2 - 2ps ----------------
__global__ __launch_bounds__(256) void right_kernel(const float* __restrict__ x,
                                                    const float* __restrict__ item_emb,
                                                    const int* __restrict__ pos_seqs,
                                                    const float* __restrict__ pred_w,
                                                    float* __restrict__ rpart) {
    __shared__ float p_s[64];
    __shared__ float red[4];
    int t = threadIdx.x;
    if (t < 64) p_s[t] = pred_w[t];
    __syncthreads();
    int w = t >> 6, lane = t & 63;
    float local = 0.f;
    for (long row = (long)blockIdx.x * 4 + w; row < NROWS; row += (long)gridDim.x * 4) {
        int pi = pos_seqs[row];
        float val = x[row * DDIM + lane] * item_emb[(long)pi * DDIM + lane] * p_s[lane];
        float ps = wave_sum(val);           // lane-uniform
        local += (1.0f - CC) * ps * ps - 2.0f * ps;   // identical on all 64 lanes
    }
    if (lane == 0) red[w] = local;
    __syncthreads();
    if (t == 0) rpart[blockIdx.x] = red[0] + red[1] + red[2] + red[3];
}

// ---------------- per-parameter sum-of-squares ----------------
struct NormEntry { const float* p; int n; };
struct NormArgs { NormEntry e[30]; };

__global__ __launch_bounds__(256) void norms_kernel(NormArgs args, float* __restrict__ norms) {
    __shared__ float red[256];
    NormEntry en = args.e[blockIdx.x];
    float s = 0.f;
    for (int i = threadIdx.x; i < en.n; i += 256) { float v = en.p[i]; s += v * v; }
    red[threadIdx.x] = s;
    for (int o = 128; o > 0; o >>= 1) {
        __syncthreads();
        if (threadIdx.x < o) red[threadIdx.x] += red[threadIdx.x + o];
    }
    __syncthreads();
    if (threadIdx.x == 0) norms[blockIdx.x] = red[0];
}

// ---------------- final scalar ----------------
__global__ __launch_bounds__(256) void final_kernel(const float* __restrict__ EE,
                                                    const float* __restrict__ FF,
                                                    const float* __restrict__ pred_w,
                                                    const float* __restrict__ rpart,
                                                    const float* __restrict__ norms,
                                                    float* __restrict__ out) {
    __shared__ float p_s[64];
    __shared__ float redL[256];
    __shared__ float redT[256];
    __shared__ float redR[256];
    int t = threadIdx.x;
    if (t < 64) p_s[t] = pred_w[t];
    __syncthreads();
    float lf = 0.f, tr = 0.f, rs = 0.f;
    for (int p = t; p < 4096; p += 256) {
        int i = p >> 6, j = p & 63;
        float ee = EE[p];
        lf += FF[p] * ee * p_s[i] * p_s[j];
        if (i == j) tr += ee;
    }
    for (int i = t; i < 1024; i += 256) rs += rpart[i];
    redL[t] = lf; redT[t] = tr; redR[t] = rs;
    for (int o = 128; o > 0; o >>= 1) {
        __syncthreads();
        if (t < o) { redL[t] += redL[t + o]; redT[t] += redT[t + o]; redR[t] += redR[t + o]; }
    }
    __syncthreads();
    if (t == 0) {
        float reg = sqrtf(redT[0]);   // ||item_emb||_F = sqrt(trace(EE))
        for (int s = 0; s < 30; ++s) reg += sqrtf(norms[s]);
        out[0] = CC * redL[0] + redR[0] + 0.1f * reg;
    }
}

// ---------------- host ----------------
struct DevPtrs { float *x, *qin, *q, *k, *v, *ctx, *gpart; };

static DevPtrs fetch_ptrs() {
    DevPtrs p;
    (void)hipGetSymbolAddress((void**)&p.x,    HIP_SYMBOL(g_x));
    (void)hipGetSymbolAddress((void**)&p.qin,  HIP_SYMBOL(g_qin));
    (void)hipGetSymbolAddress((void**)&p.q,    HIP_SYMBOL(g_q));
    (void)hipGetSymbolAddress((void**)&p.k,    HIP_SYMBOL(g_k));
    (void)hipGetSymbolAddress((void**)&p.v,    HIP_SYMBOL(g_v));
    (void)hipGetSymbolAddress((void**)&p.ctx,  HIP_SYMBOL(g_ctx));
    (void)hipGetSymbolAddress((void**)&p.gpart,HIP_SYMBOL(g_gpart));
    return p;
}

extern "C" void kernel_launch(void* const* d_in, const int* in_sizes, int n_in,
                              void* d_out, int out_size, void* d_ws, size_t ws_size,
                              hipStream_t stream) {
    const int*   log_seqs = (const int*)d_in[1];
    const int*   pos_seqs = (const int*)d_in[2];
    const float* item_emb = (const float*)d_in[3];
    const float* pos_emb  = (const float*)d_in[4];
    const float* pred_w   = (const float*)d_in[5];
    const float* ln_w     = (const float*)d_in[6];
    const float* ln_b     = (const float*)d_in[7];
    const float* qkv_w    = (const float*)d_in[8];
    const float* qkv_b    = (const float*)d_in[9];
    const float* out_w    = (const float*)d_in[10];
    const float* out_b    = (const float*)d_in[11];
    const float* fc1_w    = (const float*)d_in[12];
    const float* fc1_b    = (const float*)d_in[13];
    const float* ffln_w   = (const float*)d_in[14];
    const float* ffln_b   = (const float*)d_in[15];
    const float* fc2_w    = (const float*)d_in[16];
    const float* fc2_b    = (const float*)d_in[17];
    const float* ffln2_w  = (const float*)d_in[18];
    const float* ffln2_b  = (const float*)d_in[19];

    static DevPtrs P = fetch_ptrs();   // first call is the uncaptured correctness call

    float* ws    = (float*)d_ws;
    float* rpart = ws;            // 1024
    float* nrm   = ws + 1024;     // 30
    float* EE    = ws + 2048;     // 4096
    float* FF    = ws + 6144;     // 4096

    embed_kernel<<<NROWS * 16 / 256, 256, 0, stream>>>(log_seqs, item_emb, pos_emb, P.x);

    const int GEMM_GRID = NROWS / 64;   // 1600

    for (int l = 0; l < LL; ++l) {
        const float* Wqkv = qkv_w + (long)l * 3 * 64 * 64;
        const float* Bqkv = qkv_b + (long)l * 192;
        qkv_fused<<<GEMM_GRID, 256, 0, stream>>>(
            P.x, Wqkv, Bqkv, ln_w + l * 64, ln_b + l * 64, P.qin, P.q, P.k, P.v);
        attn_kernel<<<BB * 2, 512, 0, stream>>>(P.q, P.k, P.v, P.ctx);
        ffn_fused<<<GEMM_GRID, 256, 0, stream>>>(
            P.ctx, P.qin,
            out_w + (long)l * 4096, out_b + l * 64,
            fc1_w + (long)l * 4096, fc1_b + l * 64,
            fc2_w + (long)l * 4096, fc2_b + l * 64,
            ffln_w + l * 64, ffln_b + l * 64,
            ffln2_w + l * 64, ffln2_b + l * 64,
            P.x);
    }

    gram_kernel<<<GRAM_NB, 256, 0, stream>>>(item_emb, 100001, P.gpart);
    gram_reduce<<<16, 256, 0, stream>>>(P.gpart, EE);
    gram_kernel<<<GRAM_NB, 256, 0, stream>>>(P.x, NROWS, P.gpart);
    gram_reduce<<<16, 256, 0, stream>>>(P.gpart, FF);
    right_kernel<<<1024, 256, 0, stream>>>(P.x, item_emb, pos_seqs, pred_w, rpart);

    NormArgs na;
    int s = 0;
    na.e[s++] = {pos_emb, (SS + 1) * DDIM};
    na.e[s++] = {pred_w, DDIM};
    for (int l = 0; l < LL; ++l) {
        na.e[s++] = {ln_w + l * 64, 64};
        na.e[s++] = {ln_b + l * 64, 64};
        na.e[s++] = {qkv_w + (long)l * 12288, 12288};
        na.e[s++] = {qkv_b + (long)l * 192, 192};
        na.e[s++] = {out_w + (long)l * 4096, 4096};
        na.e[s++] = {out_b + l * 64, 64};
        na.e[s++] = {fc1_w + (long)l * 4096, 4096};
        na.e[s++] = {fc1_b + l * 64, 64};
        na.e[s++] = {ffln_w + l * 64, 64};
        na.e[s++] = {ffln_b + l * 64, 64};
        na.e[s++] = {fc2_w + (long)l * 4096, 4096};
        na.e[s++] = {fc2_b + l * 64, 64};
        na.e[s++] = {ffln2_w + l * 64, 64};
        na.e[s++] = {ffln2_b + l * 64, 64};
    }
    norms_kernel<<<30, 256, 0, stream>>>(na, nrm);

    final_kernel<<<1, 256, 0, stream>>>(EE, FF, pred_w, rpart, nrm, (float*)d_out);
}